// Round 4
// baseline (92.442 us; speedup 1.0000x reference)
//
#include <hip/hip_runtime.h>

#define CDIM 256
#define NDET 900
#define NMAP 100
#define NPTS 20
#define NBLK (NDET + NMAP)

__global__ __launch_bounds__(256) void autonav_fused(
    const float* __restrict__ p2, const float* __restrict__ p3,
    const float* __restrict__ p4, const float* __restrict__ p5,
    const float* __restrict__ Kin, const float* __restrict__ Ein,
    const float* __restrict__ det3d, const float* __restrict__ detfull,
    const float* __restrict__ mapanch,
    const float* __restrict__ W1d, const float* __restrict__ b1d,
    const float* __restrict__ Wcd, const float* __restrict__ bcd,
    const float* __restrict__ Wod, const float* __restrict__ bod,
    const float* __restrict__ W1m, const float* __restrict__ b1m,
    const float* __restrict__ Wcm, const float* __restrict__ bcm,
    const float* __restrict__ Wom, const float* __restrict__ bom,
    float* __restrict__ out)
{
    const int pt = blockIdx.x;      // 0..999: 0..899 det, 900..999 map
    const int t  = threadIdx.x;     // channel
    const bool isDet = (pt < NDET);
    const int m = pt - NDET;

    __shared__ float s_gx[6], s_gy[6];
    __shared__ int   s_valid[6];
    __shared__ float s_homo[4];
    __shared__ int   s_off[24][4];  // (cam*4+level) x corner
    __shared__ float s_w[24][4];
    __shared__ float s_vec[CDIM];

    // ---- homogeneous point ----
    if (t == 0) {
        float h0, h1, h2;
        if (isDet) {
            h0 = det3d[pt * 3 + 0];
            h1 = det3d[pt * 3 + 1];
            h2 = det3d[pt * 3 + 2];
        } else {
            float cx = 0.f, cy = 0.f;
            for (int j = 0; j < NPTS; ++j) {
                cx += mapanch[(m * NPTS + j) * 2 + 0];
                cy += mapanch[(m * NPTS + j) * 2 + 1];
            }
            h0 = cx / (float)NPTS;
            h1 = cy / (float)NPTS;
            h2 = 0.f;
        }
        s_homo[0] = h0; s_homo[1] = h1; s_homo[2] = h2; s_homo[3] = 1.f;
    }
    __syncthreads();

    // ---- projection (one thread per camera) ----
    if (t < 6) {
        const int cam = t;
        const float h0 = s_homo[0], h1 = s_homo[1], h2 = s_homo[2], h3 = s_homo[3];
        float pc[3];
        #pragma unroll
        for (int i = 0; i < 3; ++i) {
            pc[i] = Ein[cam * 16 + i * 4 + 0] * h0
                  + Ein[cam * 16 + i * 4 + 1] * h1
                  + Ein[cam * 16 + i * 4 + 2] * h2
                  + Ein[cam * 16 + i * 4 + 3] * h3;
        }
        const float q0 = Kin[cam * 9 + 0] * pc[0] + Kin[cam * 9 + 1] * pc[1] + Kin[cam * 9 + 2] * pc[2];
        const float q1 = Kin[cam * 9 + 3] * pc[0] + Kin[cam * 9 + 4] * pc[1] + Kin[cam * 9 + 5] * pc[2];
        const float q2 = Kin[cam * 9 + 6] * pc[0] + Kin[cam * 9 + 7] * pc[1] + Kin[cam * 9 + 8] * pc[2];
        const float depth = q2;
        const float u = q0 / (depth + 1e-6f);
        const float v = q1 / (depth + 1e-6f);
        s_valid[cam] = (depth > 0.1f) ? 1 : 0;
        s_gx[cam] = u / 640.0f * 2.0f - 1.0f;
        s_gy[cam] = v / 480.0f * 2.0f - 1.0f;
    }
    __syncthreads();

    // ---- per (cam, level) bilinear setup ----
    if (t < 24) {
        const int cam = t >> 2, l = t & 3;
        const int Hs[4] = {120, 60, 30, 15};
        const int Ws[4] = {160, 80, 40, 20};
        const int H = Hs[l], W = Ws[l];
        const float gx = s_gx[cam], gy = s_gy[cam];
        const float x = (gx + 1.f) * (W * 0.5f) - 0.5f;
        const float y = (gy + 1.f) * (H * 0.5f) - 0.5f;
        const float x0f = floorf(x), y0f = floorf(y);
        const float wx1 = x - x0f, wx0 = 1.f - wx1;
        const float wy1 = y - y0f, wy0 = 1.f - wy1;
        const float x1f = x0f + 1.f, y1f = y0f + 1.f;
        const bool bx0 = (x0f >= 0.f) && (x0f <= (float)(W - 1));
        const bool bx1 = (x1f >= 0.f) && (x1f <= (float)(W - 1));
        const bool by0 = (y0f >= 0.f) && (y0f <= (float)(H - 1));
        const bool by1 = (y1f >= 0.f) && (y1f <= (float)(H - 1));
        const int xc0 = (int)fminf(fmaxf(x0f, 0.f), (float)(W - 1));
        const int xc1 = (int)fminf(fmaxf(x1f, 0.f), (float)(W - 1));
        const int yc0 = (int)fminf(fmaxf(y0f, 0.f), (float)(H - 1));
        const int yc1 = (int)fminf(fmaxf(y1f, 0.f), (float)(H - 1));
        const int base = cam * CDIM * H * W;
        s_off[t][0] = base + yc0 * W + xc0;
        s_off[t][1] = base + yc0 * W + xc1;
        s_off[t][2] = base + yc1 * W + xc0;
        s_off[t][3] = base + yc1 * W + xc1;
        s_w[t][0] = (bx0 && by0) ? wx0 * wy0 : 0.f;
        s_w[t][1] = (bx1 && by0) ? wx1 * wy0 : 0.f;
        s_w[t][2] = (bx0 && by1) ? wx0 * wy1 : 0.f;
        s_w[t][3] = (bx1 && by1) ? wx1 * wy1 : 0.f;
    }
    __syncthreads();

    // ---- multiscale multi-camera gather-accumulate (thread = channel) ----
    const float* fptr[4] = {p2, p3, p4, p5};
    const int HWs[4] = {120 * 160, 60 * 80, 30 * 40, 15 * 20};
    float acc = 0.f;
    #pragma unroll
    for (int l = 0; l < 4; ++l) {
        const float* __restrict__ f = fptr[l];
        const int cHW = t * HWs[l];
        #pragma unroll
        for (int cam = 0; cam < 6; ++cam) {
            if (!s_valid[cam]) continue;
            const int tt = cam * 4 + l;
            const float v0 = f[s_off[tt][0] + cHW];
            const float v1 = f[s_off[tt][1] + cHW];
            const float v2 = f[s_off[tt][2] + cHW];
            const float v3 = f[s_off[tt][3] + cHW];
            acc += s_w[tt][0] * v0 + s_w[tt][1] * v1 + s_w[tt][2] * v2 + s_w[tt][3] * v3;
        }
    }
    // /4 (levels) then /6 (cams), like the reference
    const float agg = (acc * 0.25f) / 6.0f;

    s_vec[t] = agg;
    __syncthreads();

    // ---- hidden layer GEMV: h = relu(agg @ W1 + b1) ----
    const float* __restrict__ W1 = isDet ? W1d : W1m;
    const float* __restrict__ b1 = isDet ? b1d : b1m;
    float hsum = b1[t];
    #pragma unroll 8
    for (int k = 0; k < CDIM; ++k) {
        hsum = fmaf(s_vec[k], W1[k * CDIM + t], hsum);
    }
    const float hval = fmaxf(hsum, 0.f);
    __syncthreads();
    s_vec[t] = hval;
    __syncthreads();

    // ---- output heads (f32 out) ----
    const int NO = isDet ? 15 : 43;
    if (t < NO) {
        const float* Wp; const float* bp;
        int stride, o, ooff;
        float addv = 0.f;
        if (isDet) {
            if (t < 4)  { Wp = Wcd; bp = bcd; stride = 4;  o = t;     ooff = pt * 4 + o; }
            else        { Wp = Wod; bp = bod; stride = 11; o = t - 4; ooff = 3600 + pt * 11 + o;
                          addv = detfull[pt * 11 + o]; }
        } else {
            if (t < 3)  { Wp = Wcm; bp = bcm; stride = 3;  o = t;     ooff = 13500 + m * 3 + o; }
            else        { Wp = Wom; bp = bom; stride = 40; o = t - 3; ooff = 13800 + m * 40 + o;
                          addv = mapanch[m * 40 + o]; }
        }
        float s = bp[o] + addv;
        for (int k = 0; k < CDIM; ++k) {
            s = fmaf(s_vec[k], Wp[k * stride + o], s);
        }
        out[ooff] = s;
    }
}

extern "C" void kernel_launch(void* const* d_in, const int* in_sizes, int n_in,
                              void* d_out, int out_size, void* d_ws, size_t ws_size,
                              hipStream_t stream) {
    const float* p2      = (const float*)d_in[0];
    const float* p3      = (const float*)d_in[1];
    const float* p4      = (const float*)d_in[2];
    const float* p5      = (const float*)d_in[3];
    const float* Kin     = (const float*)d_in[4];
    const float* Ein     = (const float*)d_in[5];
    const float* det3d   = (const float*)d_in[6];
    const float* detfull = (const float*)d_in[7];
    const float* mapanch = (const float*)d_in[8];
    const float* W1d     = (const float*)d_in[9];
    const float* b1d     = (const float*)d_in[10];
    const float* Wcd     = (const float*)d_in[11];
    const float* bcd     = (const float*)d_in[12];
    const float* Wod     = (const float*)d_in[13];
    const float* bod     = (const float*)d_in[14];
    const float* W1m     = (const float*)d_in[15];
    const float* b1m     = (const float*)d_in[16];
    const float* Wcm     = (const float*)d_in[17];
    const float* bcm     = (const float*)d_in[18];
    const float* Wom     = (const float*)d_in[19];
    const float* bom     = (const float*)d_in[20];
    float* out = (float*)d_out;

    autonav_fused<<<NBLK, 256, 0, stream>>>(
        p2, p3, p4, p5, Kin, Ein, det3d, detfull, mapanch,
        W1d, b1d, Wcd, bcd, Wod, bod, W1m, b1m, Wcm, bcm, Wom, bom, out);
}

// Round 5
// 55.643 us; speedup vs baseline: 1.6614x; 1.6614x over previous
//
#include <hip/hip_runtime.h>

#define CDIM 256
#define NDET 900
#define NMAP 100
#define NPTS 20
#define NBLK (NDET + NMAP)

__device__ __forceinline__ const float* lvlPtr(int l, const float* p2, const float* p3,
                                               const float* p4, const float* p5) {
    return (l == 0) ? p2 : (l == 1) ? p3 : (l == 2) ? p4 : p5;
}
__device__ __forceinline__ int lvlHW(int l) {
    return (l == 0) ? 19200 : (l == 1) ? 4800 : (l == 2) ? 1200 : 300;
}

__global__ __launch_bounds__(256) void autonav_fused(
    const float* __restrict__ p2, const float* __restrict__ p3,
    const float* __restrict__ p4, const float* __restrict__ p5,
    const float* __restrict__ Kin, const float* __restrict__ Ein,
    const float* __restrict__ det3d, const float* __restrict__ detfull,
    const float* __restrict__ mapanch,
    const float* __restrict__ W1d, const float* __restrict__ b1d,
    const float* __restrict__ Wcd, const float* __restrict__ bcd,
    const float* __restrict__ Wod, const float* __restrict__ bod,
    const float* __restrict__ W1m, const float* __restrict__ b1m,
    const float* __restrict__ Wcm, const float* __restrict__ bcm,
    const float* __restrict__ Wom, const float* __restrict__ bom,
    float* __restrict__ out)
{
    const int pt = blockIdx.x;      // 0..999: 0..899 det, 900..999 map
    const int t  = threadIdx.x;     // channel
    const bool isDet = (pt < NDET);
    const int m = pt - NDET;

    __shared__ float s_gx[6], s_gy[6];
    __shared__ int   s_valid[6];
    __shared__ float s_homo[4];
    __shared__ int   s_off[24][4];  // (cam*4+level) x corner
    __shared__ float s_w[24][4];
    __shared__ float s_vec[CDIM];
    __shared__ int   s_list[24];
    __shared__ int   s_n;

    // ---- homogeneous point ----
    if (t == 0) {
        float h0, h1, h2;
        if (isDet) {
            h0 = det3d[pt * 3 + 0];
            h1 = det3d[pt * 3 + 1];
            h2 = det3d[pt * 3 + 2];
        } else {
            float cx = 0.f, cy = 0.f;
            for (int j = 0; j < NPTS; ++j) {
                cx += mapanch[(m * NPTS + j) * 2 + 0];
                cy += mapanch[(m * NPTS + j) * 2 + 1];
            }
            h0 = cx / (float)NPTS;
            h1 = cy / (float)NPTS;
            h2 = 0.f;
        }
        s_homo[0] = h0; s_homo[1] = h1; s_homo[2] = h2; s_homo[3] = 1.f;
    }
    __syncthreads();

    // ---- projection (one thread per camera) ----
    if (t < 6) {
        const int cam = t;
        const float h0 = s_homo[0], h1 = s_homo[1], h2 = s_homo[2], h3 = s_homo[3];
        float pc[3];
        #pragma unroll
        for (int i = 0; i < 3; ++i) {
            pc[i] = Ein[cam * 16 + i * 4 + 0] * h0
                  + Ein[cam * 16 + i * 4 + 1] * h1
                  + Ein[cam * 16 + i * 4 + 2] * h2
                  + Ein[cam * 16 + i * 4 + 3] * h3;
        }
        const float q0 = Kin[cam * 9 + 0] * pc[0] + Kin[cam * 9 + 1] * pc[1] + Kin[cam * 9 + 2] * pc[2];
        const float q1 = Kin[cam * 9 + 3] * pc[0] + Kin[cam * 9 + 4] * pc[1] + Kin[cam * 9 + 5] * pc[2];
        const float q2 = Kin[cam * 9 + 6] * pc[0] + Kin[cam * 9 + 7] * pc[1] + Kin[cam * 9 + 8] * pc[2];
        const float depth = q2;
        const float u = q0 / (depth + 1e-6f);
        const float v = q1 / (depth + 1e-6f);
        s_valid[cam] = (depth > 0.1f) ? 1 : 0;
        s_gx[cam] = u / 640.0f * 2.0f - 1.0f;
        s_gy[cam] = v / 480.0f * 2.0f - 1.0f;
    }
    __syncthreads();

    // ---- per (cam, level) bilinear setup ----
    if (t < 24) {
        const int cam = t >> 2, l = t & 3;
        const int Hs[4] = {120, 60, 30, 15};
        const int Ws[4] = {160, 80, 40, 20};
        const int H = Hs[l], W = Ws[l];
        const float gx = s_gx[cam], gy = s_gy[cam];
        const float x = (gx + 1.f) * (W * 0.5f) - 0.5f;
        const float y = (gy + 1.f) * (H * 0.5f) - 0.5f;
        const float x0f = floorf(x), y0f = floorf(y);
        const float wx1 = x - x0f, wx0 = 1.f - wx1;
        const float wy1 = y - y0f, wy0 = 1.f - wy1;
        const float x1f = x0f + 1.f, y1f = y0f + 1.f;
        const bool bx0 = (x0f >= 0.f) && (x0f <= (float)(W - 1));
        const bool bx1 = (x1f >= 0.f) && (x1f <= (float)(W - 1));
        const bool by0 = (y0f >= 0.f) && (y0f <= (float)(H - 1));
        const bool by1 = (y1f >= 0.f) && (y1f <= (float)(H - 1));
        const int xc0 = (int)fminf(fmaxf(x0f, 0.f), (float)(W - 1));
        const int xc1 = (int)fminf(fmaxf(x1f, 0.f), (float)(W - 1));
        const int yc0 = (int)fminf(fmaxf(y0f, 0.f), (float)(H - 1));
        const int yc1 = (int)fminf(fmaxf(y1f, 0.f), (float)(H - 1));
        const int base = cam * CDIM * H * W;
        s_off[t][0] = base + yc0 * W + xc0;
        s_off[t][1] = base + yc0 * W + xc1;
        s_off[t][2] = base + yc1 * W + xc0;
        s_off[t][3] = base + yc1 * W + xc1;
        s_w[t][0] = (bx0 && by0) ? wx0 * wy0 : 0.f;
        s_w[t][1] = (bx1 && by0) ? wx1 * wy0 : 0.f;
        s_w[t][2] = (bx0 && by1) ? wx0 * wy1 : 0.f;
        s_w[t][3] = (bx1 && by1) ? wx1 * wy1 : 0.f;
    }
    __syncthreads();

    // ---- compact list of tiles with nonzero contribution (deterministic) ----
    if (t == 0) {
        int n = 0;
        for (int tt = 0; tt < 24; ++tt) {
            const int cam = tt >> 2;
            const float wsum = s_w[tt][0] + s_w[tt][1] + s_w[tt][2] + s_w[tt][3];
            if (s_valid[cam] && wsum != 0.f) s_list[n++] = tt;
        }
        s_n = n;
    }
    __syncthreads();

    // ---- gather-accumulate over compacted tiles, depth-2 pipeline ----
    float acc = 0.f;
    const int n = s_n;
    if (n > 0) {
        int tt = s_list[0];
        int l = tt & 3;
        const float* f = lvlPtr(l, p2, p3, p4, p5);
        int cHW = t * lvlHW(l);
        float a0 = f[s_off[tt][0] + cHW];
        float a1 = f[s_off[tt][1] + cHW];
        float a2 = f[s_off[tt][2] + cHW];
        float a3 = f[s_off[tt][3] + cHW];
        for (int j = 1; j < n; ++j) {
            const int nt = s_list[j];
            const int nl = nt & 3;
            const float* nf = lvlPtr(nl, p2, p3, p4, p5);
            const int ncHW = t * lvlHW(nl);
            const float b0 = nf[s_off[nt][0] + ncHW];
            const float b1 = nf[s_off[nt][1] + ncHW];
            const float b2 = nf[s_off[nt][2] + ncHW];
            const float b3 = nf[s_off[nt][3] + ncHW];
            acc += s_w[tt][0] * a0 + s_w[tt][1] * a1 + s_w[tt][2] * a2 + s_w[tt][3] * a3;
            tt = nt; a0 = b0; a1 = b1; a2 = b2; a3 = b3;
        }
        acc += s_w[tt][0] * a0 + s_w[tt][1] * a1 + s_w[tt][2] * a2 + s_w[tt][3] * a3;
    }
    const float agg = (acc * 0.25f) / 6.0f;

    s_vec[t] = agg;
    __syncthreads();

    // ---- hidden layer GEMV: h = relu(agg @ W1 + b1) ----
    const float* __restrict__ W1 = isDet ? W1d : W1m;
    const float* __restrict__ b1 = isDet ? b1d : b1m;
    float hsum = b1[t];
    #pragma unroll 8
    for (int k = 0; k < CDIM; ++k) {
        hsum = fmaf(s_vec[k], W1[k * CDIM + t], hsum);
    }
    const float hval = fmaxf(hsum, 0.f);
    __syncthreads();
    s_vec[t] = hval;
    __syncthreads();

    // ---- output heads (f32 out) ----
    const int NO = isDet ? 15 : 43;
    if (t < NO) {
        const float* Wp; const float* bp;
        int stride, o, ooff;
        float addv = 0.f;
        if (isDet) {
            if (t < 4)  { Wp = Wcd; bp = bcd; stride = 4;  o = t;     ooff = pt * 4 + o; }
            else        { Wp = Wod; bp = bod; stride = 11; o = t - 4; ooff = 3600 + pt * 11 + o;
                          addv = detfull[pt * 11 + o]; }
        } else {
            if (t < 3)  { Wp = Wcm; bp = bcm; stride = 3;  o = t;     ooff = 13500 + m * 3 + o; }
            else        { Wp = Wom; bp = bom; stride = 40; o = t - 3; ooff = 13800 + m * 40 + o;
                          addv = mapanch[m * 40 + o]; }
        }
        float s = bp[o] + addv;
        for (int k = 0; k < CDIM; ++k) {
            s = fmaf(s_vec[k], Wp[k * stride + o], s);
        }
        out[ooff] = s;
    }
}

extern "C" void kernel_launch(void* const* d_in, const int* in_sizes, int n_in,
                              void* d_out, int out_size, void* d_ws, size_t ws_size,
                              hipStream_t stream) {
    const float* p2      = (const float*)d_in[0];
    const float* p3      = (const float*)d_in[1];
    const float* p4      = (const float*)d_in[2];
    const float* p5      = (const float*)d_in[3];
    const float* Kin     = (const float*)d_in[4];
    const float* Ein     = (const float*)d_in[5];
    const float* det3d   = (const float*)d_in[6];
    const float* detfull = (const float*)d_in[7];
    const float* mapanch = (const float*)d_in[8];
    const float* W1d     = (const float*)d_in[9];
    const float* b1d     = (const float*)d_in[10];
    const float* Wcd     = (const float*)d_in[11];
    const float* bcd     = (const float*)d_in[12];
    const float* Wod     = (const float*)d_in[13];
    const float* bod     = (const float*)d_in[14];
    const float* W1m     = (const float*)d_in[15];
    const float* b1m     = (const float*)d_in[16];
    const float* Wcm     = (const float*)d_in[17];
    const float* bcm     = (const float*)d_in[18];
    const float* Wom     = (const float*)d_in[19];
    const float* bom     = (const float*)d_in[20];
    float* out = (float*)d_out;

    autonav_fused<<<NBLK, 256, 0, stream>>>(
        p2, p3, p4, p5, Kin, Ein, det3d, detfull, mapanch,
        W1d, b1d, Wcd, bcd, Wod, bod, W1m, b1m, Wcm, bcm, Wom, bom, out);
}